// Round 15
// baseline (363.445 us; speedup 1.0000x reference)
//
#include <hip/hip_runtime.h>

#define HID 2048
#define SEQ 2048
#define HD 128
#define QKN 6144      // 3*HID

typedef float f32x4 __attribute__((ext_vector_type(4)));
typedef short s16x8 __attribute__((ext_vector_type(8)));
typedef __bf16 bf16x8 __attribute__((ext_vector_type(8)));

static __device__ __forceinline__ unsigned short f2bf(float x) {
    unsigned u = __float_as_uint(x);
    u = u + 0x7FFFu + ((u >> 16) & 1u);   // RNE
    return (unsigned short)(u >> 16);
}
static __device__ __forceinline__ float bf2f(unsigned short h) {
    return __uint_as_float(((unsigned)h) << 16);
}
static __device__ __forceinline__ bf16x8 as_bf(s16x8 v) {
    union { s16x8 s; bf16x8 b; } u; u.s = v; return u.b;
}
static __device__ __forceinline__ bf16x8 ld_bf8(const unsigned short* p) {
    return as_bf(*(const s16x8*)p);
}
// async global->LDS, 16B/lane; LDS dest = wave-uniform base + lane*16 (m104)
static __device__ __forceinline__ void gload_lds16(const void* g, void* l) {
    __builtin_amdgcn_global_load_lds(
        (const __attribute__((address_space(1))) void*)g,
        (__attribute__((address_space(3))) void*)l,
        16, 0, 0);
}

__global__ __launch_bounds__(256) void fill_f32(
    float* __restrict__ out, float v, int n)
{
    int i = blockIdx.x * 256 + threadIdx.x;
    if (i < n) out[i] = v;
}

// ---------------- fp32 -> bf16 convert (8 elems/thread) ----------------
__global__ __launch_bounds__(256) void convert_f32_bf16(
    const float* __restrict__ in, unsigned short* __restrict__ out)
{
    long i = ((long)blockIdx.x * 256 + threadIdx.x) * 8;
    f32x4 a = *(const f32x4*)&in[i];
    f32x4 b = *(const f32x4*)&in[i + 4];
    s16x8 o;
#pragma unroll
    for (int e = 0; e < 4; ++e) {
        o[e]     = (short)f2bf(a[e]);
        o[e + 4] = (short)f2bf(b[e]);
    }
    *(s16x8*)&out[i] = o;
}

// ---------------- W[k][n] fp32 -> Wt[n][k] bf16 (tiled transpose) ----------------
__global__ __launch_bounds__(256) void transpose_w(
    const float* __restrict__ W, unsigned short* __restrict__ Wt)
{
    __shared__ float t[32][33];
    int k0 = blockIdx.x * 32, n0 = blockIdx.y * 32;
    int tx = threadIdx.x & 31, ty = threadIdx.x >> 5;
#pragma unroll
    for (int r = ty; r < 32; r += 8)
        t[r][tx] = W[(long)(k0 + r) * HID + n0 + tx];
    __syncthreads();
#pragma unroll
    for (int r = ty; r < 32; r += 8)
        Wt[(long)(n0 + r) * HID + k0 + tx] = f2bf(t[tx][r]);
}

// ======== 256xBN single-phase GEMM: read each fragment ONCE per K-tile ====
// dbuf LDS; counted vmcnt; setprio around MFMA clusters; 2-D XCD chunking.
template<int NF, bool F32OUT>
__global__ __launch_bounds__(512, 2) void gemm_8phase(
    const unsigned short* __restrict__ A,    // [M][K] bf16
    const unsigned short* __restrict__ Bt,   // [N][K] bf16
    const float* __restrict__ bq, const float* __restrict__ bk,
    const float* __restrict__ bv,
    unsigned short* __restrict__ Cb, float* __restrict__ Cf,
    int K, int ldc, int nbn, int sm, int sn, int hasBias)
{
    constexpr int BUFE = 16384 + NF * 4096;      // elems per LDS buffer (A|B)
    __shared__ unsigned short lds[2 * BUFE];
    const int tid = threadIdx.x;
    const int wid = tid >> 6, lane = tid & 63;
    const int l16 = lane & 15, l4 = lane >> 4;
    const int wm = wid >> 2, wn = wid & 3;

    // 2-D XCD chunk decode: 8 chunks of sm x sn tiles
    const int bid = blockIdx.x;
    const int xcd = bid & 7, idx = bid >> 3;
    const int ncn = nbn / sn;                    // chunk-cols
    const int cm = xcd / ncn, cn = xcd % ncn;
    const int lm = idx / sn,  ln = idx % sn;
    const long bm = (long)(cm * sm + lm) * 256;
    const long bn = (long)(cn * sn + ln) * (NF * 64);

    const int NT = K >> 6;
    const long strideB = (long)K * 2;            // bytes per global row
    const int srow = tid >> 3;                   // 0..63 row within 64-row chunk
    const int scb  = ((tid & 7) * 16) ^ ((srow & 7) << 4);   // pre-swizzled src byte

    auto stageA = [&](int t, int c) {            // c in 0..3
        unsigned short* base = &lds[(t & 1) * BUFE];
        const int row = c * 64 + srow;
        const char* src = (const char*)A + (bm + row) * strideB + (long)t * 128 + scb;
        gload_lds16(src, base + (c * 64 + wid * 8) * 64);
    };
    auto stageB = [&](int t, int c) {            // c in 0..NF-1
        unsigned short* base = &lds[(t & 1) * BUFE + 16384];
        const int row = c * 64 + srow;
        const char* src = (const char*)Bt + (bn + row) * strideB + (long)t * 128 + scb;
        gload_lds16(src, base + (c * 64 + wid * 8) * 64);
    };

    f32x4 acc[8][NF];
#pragma unroll
    for (int i = 0; i < 8; ++i)
#pragma unroll
        for (int j = 0; j < NF; ++j) acc[i][j] = f32x4{0.f, 0.f, 0.f, 0.f};

    // compute one K-tile: every fragment read exactly once (A in 2 halves)
    auto compute = [&](const unsigned short* Ab, const unsigned short* Bb) {
        bf16x8 bfr[NF][2];
#pragma unroll
        for (int j = 0; j < NF; ++j) {
            const int row = wn * (NF * 16) + j * 16 + l16;
            const char* rb = (const char*)Bb + row * 128;
#pragma unroll
            for (int kk = 0; kk < 2; ++kk)
                bfr[j][kk] = as_bf(*(const s16x8*)(rb + ((kk * 64 + l4 * 16) ^ ((l16 & 7) << 4))));
        }
#pragma unroll
        for (int half = 0; half < 2; ++half) {
            bf16x8 af[4][2];
#pragma unroll
            for (int i = 0; i < 4; ++i) {
                const int row = wm * 128 + (half * 4 + i) * 16 + l16;
                const char* rb = (const char*)Ab + row * 128;
#pragma unroll
                for (int kk = 0; kk < 2; ++kk)
                    af[i][kk] = as_bf(*(const s16x8*)(rb + ((kk * 64 + l4 * 16) ^ ((l16 & 7) << 4))));
            }
            __builtin_amdgcn_s_setprio(1);
#pragma unroll
            for (int kk = 0; kk < 2; ++kk)
#pragma unroll
                for (int i = 0; i < 4; ++i)
#pragma unroll
                    for (int j = 0; j < NF; ++j)
                        acc[half * 4 + i][j] = __builtin_amdgcn_mfma_f32_16x16x32_bf16(
                            af[i][kk], bfr[j][kk], acc[half * 4 + i][j], 0, 0, 0);
            __builtin_amdgcn_s_setprio(0);
        }
    };

    // prologue: stage tile 0 fully
#pragma unroll
    for (int c = 0; c < 4; ++c) stageA(0, c);
#pragma unroll
    for (int c = 0; c < NF; ++c) stageB(0, c);

    for (int t = 0; t < NT - 1; ++t) {
        const unsigned short* Ab = &lds[(t & 1) * BUFE];
        const unsigned short* Bb = Ab + 16384;
#pragma unroll
        for (int c = 0; c < 4; ++c) stageA(t + 1, c);
#pragma unroll
        for (int c = 0; c < NF; ++c) stageB(t + 1, c);
        __builtin_amdgcn_sched_barrier(0);
        if constexpr (NF == 3) asm volatile("s_waitcnt vmcnt(7)" ::: "memory");
        else                   asm volatile("s_waitcnt vmcnt(6)" ::: "memory");
        __builtin_amdgcn_s_barrier();
        __builtin_amdgcn_sched_barrier(0);                 // no ds_read above validity
        compute(Ab, Bb);
        __builtin_amdgcn_s_barrier();   // all reads of buf done before t+2 staging
    }
    {
        const unsigned short* Ab = &lds[((NT - 1) & 1) * BUFE];
        const unsigned short* Bb = Ab + 16384;
        asm volatile("s_waitcnt vmcnt(0)" ::: "memory");
        __builtin_amdgcn_s_barrier();
        __builtin_amdgcn_sched_barrier(0);
        compute(Ab, Bb);
    }

    // epilogue: C/D map col=l16, row=l4*4+r (m89)
#pragma unroll
    for (int nf = 0; nf < NF; ++nf) {
        const long n = bn + wn * (NF * 16) + nf * 16 + l16;
        float bvv = 0.f;
        if (hasBias)
            bvv = (n < HID) ? bq[n] : ((n < 2 * HID) ? bk[n - HID] : bv[n - 2 * HID]);
#pragma unroll
        for (int mf = 0; mf < 8; ++mf) {
#pragma unroll
            for (int r = 0; r < 4; ++r) {
                const long m = bm + wm * 128 + mf * 16 + l4 * 4 + r;
                float v = acc[mf][nf][r] + bvv;
                if (F32OUT) Cf[m * (long)ldc + n] = v;
                else        Cb[m * (long)ldc + n] = f2bf(v);
            }
        }
    }
}

// ---------------- RoPE in place on Q,K halves; folds 1/sqrt(128) into Q ------
__global__ __launch_bounds__(256) void rope_kernel(unsigned short* __restrict__ qkv)
{
    int t = blockIdx.x * 256 + threadIdx.x;   // 1,048,576 total
    int j8 = t & 7;
    int h  = (t >> 3) & 15;
    int qk = (t >> 7) & 1;                    // 0 = Q, 1 = K
    int row = t >> 8;                         // 0..4095
    int s = row & (SEQ - 1);
    unsigned short* p = &qkv[(long)row * QKN + qk * HID + h * HD + j8 * 8];
    s16x8 lo = *(const s16x8*)p;
    s16x8 hi = *(const s16x8*)(p + 64);
    float qscale = qk ? 1.0f : 0.08838834764831845f;
    s16x8 olo, ohi;
#pragma unroll
    for (int e = 0; e < 8; ++e) {
        int j = j8 * 8 + e;                   // 0..63
        float inv = exp2f(-(float)j * 0.20762050593046f);  // 10000^(-j/64)
        float sn, cs;
        sincosf((float)s * inv, &sn, &cs);
        float x1 = bf2f((unsigned short)lo[e]);
        float x2 = bf2f((unsigned short)hi[e]);
        olo[e] = (short)f2bf((x1 * cs - x2 * sn) * qscale);
        ohi[e] = (short)f2bf((x2 * cs + x1 * sn) * qscale);
    }
    *(s16x8*)p = olo;
    *(s16x8*)(p + 64) = ohi;
}

// ---------------- V[b,s,h,d] -> VT[b,h,d,s] ----------------
__global__ __launch_bounds__(256) void v_transpose(
    const unsigned short* __restrict__ qkv, unsigned short* __restrict__ vt)
{
    __shared__ unsigned short t[32][33];
    int bh = blockIdx.z;
    int b = bh >> 4, h = bh & 15;
    int s0 = blockIdx.x * 32, d0 = blockIdx.y * 32;
    int tx = threadIdx.x & 31, ty = threadIdx.x >> 5;
#pragma unroll
    for (int r = ty; r < 32; r += 8)
        t[r][tx] = qkv[(long)(b * SEQ + s0 + r) * QKN + 2 * HID + h * HD + d0 + tx];
    __syncthreads();
#pragma unroll
    for (int r = ty; r < 32; r += 8)
        vt[((long)bh * HD + d0 + r) * SEQ + s0 + tx] = t[tx][r];
}

// -------- MFMA flash attention r15: 4 waves x 32 q-rows (QBLK=128).
// Each kf/vb LDS fragment is read ONCE and feeds TWO q-group MFMAs -> LDS
// read traffic per q-row halved (was 8 waves x redundant reads, LDS-bound).
// T2 swizzles, dbuf staging, defer-max, swapped-QK^T in-register softmax.
__global__ __launch_bounds__(256) void attn_kernel(
    const unsigned short* __restrict__ qkv,
    const unsigned short* __restrict__ vt,
    unsigned short* __restrict__ attnout)
{
    __shared__ unsigned short Ks[2][64 * 128];   // [kv][d], byte ^= (kv&7)<<4
    __shared__ unsigned short Vs[2][128 * 64];   // [d][kv], byte ^= (d&7)<<4

    const int tid = threadIdx.x, wid = tid >> 6, lane = tid & 63;
    const int l16 = lane & 15, l4 = lane >> 4;
    const int bid = blockIdx.x;                  // 0..511
    const int xcd = bid & 7, idx = bid >> 3;     // idx 0..63
    const int bh = xcd * 4 + (idx >> 4);         // 4 heads per XCD
    const int qt = idx & 15;                     // 16 q-tiles (QBLK=128)
    const int b = bh >> 4, h = bh & 15;
    const long rowbase = (long)b * SEQ;

    const unsigned short* Kg = &qkv[rowbase * QKN + HID + h * HD];  // + s*QKN
    const unsigned short* Vg = &vt[(long)bh * HD * SEQ];            // + d*SEQ

    // 16 K chunks + 16 V chunks over 4 waves -> 4+4 per wave
    auto stage = [&](int buf, int kv0) {
#pragma unroll
        for (int i = 0; i < 4; ++i) {
            int c = wid * 4 + i;
            int kr = c * 4 + l4;
            int kcb = (l16 * 16) ^ ((kr & 7) << 4);
            gload_lds16((const char*)(Kg + (long)(kv0 + kr) * QKN) + kcb, &Ks[buf][c * 512]);
            int vr = c * 8 + (lane >> 3);
            int vcb = ((lane & 7) * 16) ^ ((vr & 7) << 4);
            gload_lds16((const char*)(Vg + (long)vr * SEQ + kv0) + vcb, &Vs[buf][c * 512]);
        }
    };

    // two q-groups per wave: rows qt*128 + wid*32 + g*16 + l16
    bf16x8 qf0[4], qf1[4];
    {
        const long qr0 = rowbase + qt * 128 + wid * 32 + l16;
        const unsigned short* qp0 = &qkv[qr0 * QKN + h * HD];
        const unsigned short* qp1 = qp0 + 16 * QKN;
#pragma unroll
        for (int kc = 0; kc < 4; ++kc) {
            qf0[kc] = ld_bf8(qp0 + kc * 32 + l4 * 8);
            qf1[kc] = ld_bf8(qp1 + kc * 32 + l4 * 8);
        }
    }

    f32x4 o0[8], o1[8];
#pragma unroll
    for (int nb = 0; nb < 8; ++nb) { o0[nb] = f32x4{0.f,0.f,0.f,0.f}; o1[nb] = f32x4{0.f,0.f,0.f,0.f}; }
    float mrun0 = -3.0e38f, lrun0 = 0.f;     // per-lane scalars (q = l16), group 0
    float mrun1 = -3.0e38f, lrun1 = 0.f;     // group 1

    const int srcA = ((l4 & 1) * 2) * 16 + l16;   // lane of l4_s = 2(l4&1)
    const int srcB = srcA + 16;                   // lane of l4_s = 2(l4&1)+1
    const bool sel = (l4 >> 1) != 0;              // nf_s = 2kc + (l4>>1)

    stage(0, 0);
    __syncthreads();

    for (int t = 0; t < SEQ / 64; ++t) {
        const int cur = t & 1;
        if (t < SEQ / 64 - 1) stage(cur ^ 1, (t + 1) * 64);
        __builtin_amdgcn_sched_barrier(0);   // pin: issue next-tile stage first

        const unsigned short* Kc = &Ks[cur][0];
        const unsigned short* Vc = &Vs[cur][0];

        // S^T = K Q^T: each kf read once, feeds both q-groups
        f32x4 sc0[4], sc1[4];
#pragma unroll
        for (int nf = 0; nf < 4; ++nf) { sc0[nf] = f32x4{0.f,0.f,0.f,0.f}; sc1[nf] = f32x4{0.f,0.f,0.f,0.f}; }
#pragma unroll
        for (int kc = 0; kc < 4; ++kc) {
#pragma unroll
            for (int nf = 0; nf < 4; ++nf) {
                int row = nf * 16 + l16;
                int cb = (kc * 64 + l4 * 16) ^ ((row & 7) << 4);
                bf16x8 kf = as_bf(*(const s16x8*)((const char*)Kc + row * 256 + cb));
                sc0[nf] = __builtin_amdgcn_mfma_f32_16x16x32_bf16(kf, qf0[kc], sc0[nf], 0, 0, 0);
                sc1[nf] = __builtin_amdgcn_mfma_f32_16x16x32_bf16(kf, qf1[kc], sc1[nf], 0, 0, 0);
            }
        }

        // per-lane max per group, combine 4 l4-copies
        float tmax0 = sc0[0][0], tmax1 = sc1[0][0];
#pragma unroll
        for (int nf = 0; nf < 4; ++nf)
#pragma unroll
            for (int r = 0; r < 4; ++r) {
                tmax0 = fmaxf(tmax0, sc0[nf][r]);
                tmax1 = fmaxf(tmax1, sc1[nf][r]);
            }
        tmax0 = fmaxf(tmax0, __shfl_xor(tmax0, 16, 64));
        tmax0 = fmaxf(tmax0, __shfl_xor(tmax0, 32, 64));
        tmax1 = fmaxf(tmax1, __shfl_xor(tmax1, 16, 64));
        tmax1 = fmaxf(tmax1, __shfl_xor(tmax1, 32, 64));

        // defer-max (T13): joint trigger; quiet group multiplies by exactly 1.0
        float grow = fmaxf(tmax0 - mrun0, tmax1 - mrun1);
        if (!__all(grow <= 8.0f)) {
            float mn0 = fmaxf(mrun0, tmax0), mn1 = fmaxf(mrun1, tmax1);
            float e0 = __expf(mrun0 - mn0), e1 = __expf(mrun1 - mn1);
            mrun0 = mn0; mrun1 = mn1;
            lrun0 *= e0;  lrun1 *= e1;
            float s0_[4], s1_[4];
#pragma unroll
            for (int r = 0; r < 4; ++r) {
                s0_[r] = __shfl(e0, l4 * 4 + r, 64);
                s1_[r] = __shfl(e1, l4 * 4 + r, 64);
            }
#pragma unroll
            for (int nb = 0; nb < 8; ++nb)
#pragma unroll
                for (int r = 0; r < 4; ++r) { o0[nb][r] *= s0_[r]; o1[nb][r] *= s1_[r]; }
        }

        // P = exp(S - m); pack to bf16 pairs; sum (both groups)
        unsigned pk0[4][2], pk1[4][2];
        float sum0 = 0.f, sum1 = 0.f;
#pragma unroll
        for (int nf = 0; nf < 4; ++nf) {
            float a0 = __expf(sc0[nf][0] - mrun0), a1 = __expf(sc0[nf][1] - mrun0);
            float a2 = __expf(sc0[nf][2] - mrun0), a3 = __expf(sc0[nf][3] - mrun0);
            sum0 += (a0 + a1) + (a2 + a3);
            union { __bf16 b[2]; unsigned u; } w0, w1;
            w0.b[0] = (__bf16)a0; w0.b[1] = (__bf16)a1;
            w1.b[0] = (__bf16)a2; w1.b[1] = (__bf16)a3;
            pk0[nf][0] = w0.u; pk0[nf][1] = w1.u;
            float b0 = __expf(sc1[nf][0] - mrun1), b1 = __expf(sc1[nf][1] - mrun1);
            float b2 = __expf(sc1[nf][2] - mrun1), b3 = __expf(sc1[nf][3] - mrun1);
            sum1 += (b0 + b1) + (b2 + b3);
            union { __bf16 b[2]; unsigned u; } x0, x1;
            x0.b[0] = (__bf16)b0; x0.b[1] = (__bf16)b1;
            x1.b[0] = (__bf16)b2; x1.b[1] = (__bf16)b3;
            pk1[nf][0] = x0.u; pk1[nf][1] = x1.u;
        }
        sum0 += __shfl_xor(sum0, 16, 64);
        sum0 += __shfl_xor(sum0, 32, 64);
        sum1 += __shfl_xor(sum1, 16, 64);
        sum1 += __shfl_xor(sum1, 32, 64);
        lrun0 += sum0; lrun1 += sum1;

        // redistribute P into PV A-fragments (4-lane group exchange), per group
        union { unsigned u[4]; bf16x8 v; } pa00, pa01, pa10, pa11;
#pragma unroll
        for (int w = 0; w < 2; ++w) {
            {
                unsigned a0 = __shfl(pk0[0][w], srcA, 64);
                unsigned a1 = __shfl(pk0[1][w], srcA, 64);
                unsigned b0 = __shfl(pk0[0][w], srcB, 64);
                unsigned b1 = __shfl(pk0[1][w], srcB, 64);
                pa00.u[w]     = sel ? a1 : a0;
                pa00.u[2 + w] = sel ? b1 : b0;
                unsigned c0 = __shfl(pk0[2][w], srcA, 64);
                unsigned c1 = __shfl(pk0[3][w], srcA, 64);
                unsigned d0 = __shfl(pk0[2][w], srcB, 64);
                unsigned d1 = __shfl(pk0[3][w], srcB, 64);
                pa01.u[w]     = sel ? c1 : c0;
                pa01.u[2 + w] = sel ? d1 : d0;
            }
            {
                unsigned a0 = __shfl(pk1[0][w], srcA, 64);
                unsigned a1 = __shfl(pk1[1][w], srcA, 64);
                unsigned b0 = __shfl(pk1[0][w], srcB, 64);
                unsigned b1 = __shfl(pk1[1][w], srcB, 64);
                pa10.u[w]     = sel ? a1 : a0;
                pa10.u[2 + w] = sel ? b1 : b0;
                unsigned c0 = __shfl(pk1[2][w], srcA, 64);
                unsigned c1 = __shfl(pk1[3][w], srcA, 64);
                unsigned d0 = __shfl(pk1[2][w], srcB, 64);
                unsigned d1 = __shfl(pk1[3][w], srcB, 64);
                pa11.u[w]     = sel ? c1 : c0;
                pa11.u[2 + w] = sel ? d1 : d0;
            }
        }

        // O += P V: each vb read once, feeds both q-groups
#pragma unroll
        for (int kc = 0; kc < 2; ++kc) {
            bf16x8 pav0 = kc ? pa01.v : pa00.v;
            bf16x8 pav1 = kc ? pa11.v : pa10.v;
#pragma unroll
            for (int nb = 0; nb < 8; ++nb) {
                int vrow = nb * 16 + l16;
                int vcb = (kc * 64 + l4 * 16) ^ ((vrow & 7) << 4);
                bf16x8 vb = as_bf(*(const s16x8*)((const char*)Vc + vrow * 128 + vcb));
                o0[nb] = __builtin_amdgcn_mfma_f32_16x16x32_bf16(pav0, vb, o0[nb], 0, 0, 0);
                o1[nb] = __builtin_amdgcn_mfma_f32_16x16x32_bf16(pav1, vb, o1[nb], 0, 0, 0);
            }
        }
        __syncthreads();   // implicit vmcnt(0): next-tile stage (issued pre-compute) done
    }

    // stats live at q=l16 lanes; o rows are q=l4*4+r -> hop via shuffles
    float li0[4], li1[4];
    {
        float linv0 = 1.f / lrun0, linv1 = 1.f / lrun1;
#pragma unroll
        for (int r = 0; r < 4; ++r) {
            li0[r] = __shfl(linv0, l4 * 4 + r, 64);
            li1[r] = __shfl(linv1, l4 * 4 + r, 64);
        }
    }
#pragma unroll
    for (int r = 0; r < 4; ++r) {
        long m0 = rowbase + qt * 128 + wid * 32 + l4 * 4 + r;
#pragma unroll
        for (int nb = 0; nb < 8; ++nb) {
            attnout[m0 * HID + h * HD + nb * 16 + l16] = f2bf(o0[nb][r] * li0[r]);
            attnout[(m0 + 16) * HID + h * HD + nb * 16 + l16] = f2bf(o1[nb][r] * li1[r]);
        }
    }
}

// ---------------- launch ----------------
extern "C" void kernel_launch(void* const* d_in, const int* in_sizes, int n_in,
                              void* d_out, int out_size, void* d_ws, size_t ws_size,
                              hipStream_t stream)
{
    const float* hs = (const float*)d_in[0];
    const float* Wq = (const float*)d_in[1];
    const float* bq = (const float*)d_in[2];
    const float* Wk = (const float*)d_in[3];
    const float* bk = (const float*)d_in[4];
    const float* Wv = (const float*)d_in[5];
    const float* bv = (const float*)d_in[6];
    const float* Wo = (const float*)d_in[7];
    float* out = (float*)d_out;   // fp32 output (confirmed round 5)

    bool shapes_ok =
        (n_in == 8) && (out_size == 8388608) &&
        in_sizes[0] == 8388608 && in_sizes[1] == 4194304 && in_sizes[2] == 2048 &&
        in_sizes[3] == 4194304 && in_sizes[4] == 2048 && in_sizes[5] == 4194304 &&
        in_sizes[6] == 2048 && in_sizes[7] == 4194304;
    if (!shapes_ok || ws_size < 117440512ull) {
        fill_f32<<<32768, 256, 0, stream>>>(out, shapes_ok ? 1000.f : 0.f, out_size);
        return;
    }

    char* ws = (char*)d_ws;
    unsigned short* hsB     = (unsigned short*)(ws);              // [4096][2048] bf16
    unsigned short* qkvB    = (unsigned short*)(ws + 16777216);   // [4096][6144] bf16
    unsigned short* wqkvT   = (unsigned short*)(ws + 67108864);   // [6144][2048] bf16
    unsigned short* vtB     = (unsigned short*)(ws + 92274688);   // [32][128][2048] bf16
    unsigned short* woT     = (unsigned short*)(ws + 109051904);  // [2048][2048] bf16
    unsigned short* attnout = hsB;   // hsB dead after QKV GEMM

    convert_f32_bf16<<<4096, 256, 0, stream>>>(hs, hsB);
    dim3 tg(64, 64);
    transpose_w<<<tg, 256, 0, stream>>>(Wq, wqkvT);
    transpose_w<<<tg, 256, 0, stream>>>(Wk, wqkvT + 2048 * 2048);
    transpose_w<<<tg, 256, 0, stream>>>(Wv, wqkvT + 2 * 2048 * 2048);
    transpose_w<<<tg, 256, 0, stream>>>(Wo, woT);

    // QKV: 256x192 tiles, 16x32 grid, XCD chunks 8x8
    gemm_8phase<3, false><<<dim3(512), 512, 0, stream>>>(
        hsB, wqkvT, bq, bk, bv, qkvB, nullptr, 2048, QKN, 32, 8, 8, 1);
    rope_kernel<<<4096, 256, 0, stream>>>(qkvB);
    v_transpose<<<dim3(64, 4, 32), 256, 0, stream>>>(qkvB, vtB);
    // attn: QBLK=128, 4 waves x 32 q-rows, 512 blocks, XCD-chunked
    attn_kernel<<<dim3(512), 256, 0, stream>>>(qkvB, vtB, attnout);
    // out-proj: 256x128 tiles, 16x16 grid, XCD chunks 4x8, fp32 out
    gemm_8phase<2, true><<<dim3(256), 512, 0, stream>>>(
        attnout, woT, nullptr, nullptr, nullptr, nullptr, out, 2048, HID, 16, 4, 8, 0);
}

// Round 16
// 312.553 us; speedup vs baseline: 1.1628x; 1.1628x over previous
//
#include <hip/hip_runtime.h>

#define HID 2048
#define SEQ 2048
#define HD 128
#define QKN 6144      // 3*HID

typedef float f32x4 __attribute__((ext_vector_type(4)));
typedef short s16x8 __attribute__((ext_vector_type(8)));
typedef __bf16 bf16x8 __attribute__((ext_vector_type(8)));

static __device__ __forceinline__ unsigned short f2bf(float x) {
    unsigned u = __float_as_uint(x);
    u = u + 0x7FFFu + ((u >> 16) & 1u);   // RNE
    return (unsigned short)(u >> 16);
}
static __device__ __forceinline__ float bf2f(unsigned short h) {
    return __uint_as_float(((unsigned)h) << 16);
}
static __device__ __forceinline__ bf16x8 as_bf(s16x8 v) {
    union { s16x8 s; bf16x8 b; } u; u.s = v; return u.b;
}
static __device__ __forceinline__ bf16x8 ld_bf8(const unsigned short* p) {
    return as_bf(*(const s16x8*)p);
}
// async global->LDS, 16B/lane; LDS dest = wave-uniform base + lane*16 (m104)
static __device__ __forceinline__ void gload_lds16(const void* g, void* l) {
    __builtin_amdgcn_global_load_lds(
        (const __attribute__((address_space(1))) void*)g,
        (__attribute__((address_space(3))) void*)l,
        16, 0, 0);
}

__global__ __launch_bounds__(256) void fill_f32(
    float* __restrict__ out, float v, int n)
{
    int i = blockIdx.x * 256 + threadIdx.x;
    if (i < n) out[i] = v;
}

// ---------------- fp32 -> bf16 convert (8 elems/thread) ----------------
__global__ __launch_bounds__(256) void convert_f32_bf16(
    const float* __restrict__ in, unsigned short* __restrict__ out)
{
    long i = ((long)blockIdx.x * 256 + threadIdx.x) * 8;
    f32x4 a = *(const f32x4*)&in[i];
    f32x4 b = *(const f32x4*)&in[i + 4];
    s16x8 o;
#pragma unroll
    for (int e = 0; e < 4; ++e) {
        o[e]     = (short)f2bf(a[e]);
        o[e + 4] = (short)f2bf(b[e]);
    }
    *(s16x8*)&out[i] = o;
}

// ---------------- W[k][n] fp32 -> Wt[n][k] bf16 (tiled transpose) ----------------
__global__ __launch_bounds__(256) void transpose_w(
    const float* __restrict__ W, unsigned short* __restrict__ Wt)
{
    __shared__ float t[32][33];
    int k0 = blockIdx.x * 32, n0 = blockIdx.y * 32;
    int tx = threadIdx.x & 31, ty = threadIdx.x >> 5;
#pragma unroll
    for (int r = ty; r < 32; r += 8)
        t[r][tx] = W[(long)(k0 + r) * HID + n0 + tx];
    __syncthreads();
#pragma unroll
    for (int r = ty; r < 32; r += 8)
        Wt[(long)(n0 + r) * HID + k0 + tx] = f2bf(t[tx][r]);
}

// ======== 256xBN single-phase GEMM: read each fragment ONCE per K-tile ====
// dbuf LDS; counted vmcnt; setprio around MFMA clusters; 2-D XCD chunking.
template<int NF, bool F32OUT>
__global__ __launch_bounds__(512, 2) void gemm_8phase(
    const unsigned short* __restrict__ A,    // [M][K] bf16
    const unsigned short* __restrict__ Bt,   // [N][K] bf16
    const float* __restrict__ bq, const float* __restrict__ bk,
    const float* __restrict__ bv,
    unsigned short* __restrict__ Cb, float* __restrict__ Cf,
    int K, int ldc, int nbn, int sm, int sn, int hasBias)
{
    constexpr int BUFE = 16384 + NF * 4096;      // elems per LDS buffer (A|B)
    __shared__ unsigned short lds[2 * BUFE];
    const int tid = threadIdx.x;
    const int wid = tid >> 6, lane = tid & 63;
    const int l16 = lane & 15, l4 = lane >> 4;
    const int wm = wid >> 2, wn = wid & 3;

    // 2-D XCD chunk decode: 8 chunks of sm x sn tiles
    const int bid = blockIdx.x;
    const int xcd = bid & 7, idx = bid >> 3;
    const int ncn = nbn / sn;                    // chunk-cols
    const int cm = xcd / ncn, cn = xcd % ncn;
    const int lm = idx / sn,  ln = idx % sn;
    const long bm = (long)(cm * sm + lm) * 256;
    const long bn = (long)(cn * sn + ln) * (NF * 64);

    const int NT = K >> 6;
    const long strideB = (long)K * 2;            // bytes per global row
    const int srow = tid >> 3;                   // 0..63 row within 64-row chunk
    const int scb  = ((tid & 7) * 16) ^ ((srow & 7) << 4);   // pre-swizzled src byte

    auto stageA = [&](int t, int c) {            // c in 0..3
        unsigned short* base = &lds[(t & 1) * BUFE];
        const int row = c * 64 + srow;
        const char* src = (const char*)A + (bm + row) * strideB + (long)t * 128 + scb;
        gload_lds16(src, base + (c * 64 + wid * 8) * 64);
    };
    auto stageB = [&](int t, int c) {            // c in 0..NF-1
        unsigned short* base = &lds[(t & 1) * BUFE + 16384];
        const int row = c * 64 + srow;
        const char* src = (const char*)Bt + (bn + row) * strideB + (long)t * 128 + scb;
        gload_lds16(src, base + (c * 64 + wid * 8) * 64);
    };

    f32x4 acc[8][NF];
#pragma unroll
    for (int i = 0; i < 8; ++i)
#pragma unroll
        for (int j = 0; j < NF; ++j) acc[i][j] = f32x4{0.f, 0.f, 0.f, 0.f};

    // compute one K-tile: every fragment read exactly once (A in 2 halves)
    auto compute = [&](const unsigned short* Ab, const unsigned short* Bb) {
        bf16x8 bfr[NF][2];
#pragma unroll
        for (int j = 0; j < NF; ++j) {
            const int row = wn * (NF * 16) + j * 16 + l16;
            const char* rb = (const char*)Bb + row * 128;
#pragma unroll
            for (int kk = 0; kk < 2; ++kk)
                bfr[j][kk] = as_bf(*(const s16x8*)(rb + ((kk * 64 + l4 * 16) ^ ((l16 & 7) << 4))));
        }
#pragma unroll
        for (int half = 0; half < 2; ++half) {
            bf16x8 af[4][2];
#pragma unroll
            for (int i = 0; i < 4; ++i) {
                const int row = wm * 128 + (half * 4 + i) * 16 + l16;
                const char* rb = (const char*)Ab + row * 128;
#pragma unroll
                for (int kk = 0; kk < 2; ++kk)
                    af[i][kk] = as_bf(*(const s16x8*)(rb + ((kk * 64 + l4 * 16) ^ ((l16 & 7) << 4))));
            }
            __builtin_amdgcn_s_setprio(1);
#pragma unroll
            for (int kk = 0; kk < 2; ++kk)
#pragma unroll
                for (int i = 0; i < 4; ++i)
#pragma unroll
                    for (int j = 0; j < NF; ++j)
                        acc[half * 4 + i][j] = __builtin_amdgcn_mfma_f32_16x16x32_bf16(
                            af[i][kk], bfr[j][kk], acc[half * 4 + i][j], 0, 0, 0);
            __builtin_amdgcn_s_setprio(0);
        }
    };

    // prologue: stage tile 0 fully
#pragma unroll
    for (int c = 0; c < 4; ++c) stageA(0, c);
#pragma unroll
    for (int c = 0; c < NF; ++c) stageB(0, c);

    for (int t = 0; t < NT - 1; ++t) {
        const unsigned short* Ab = &lds[(t & 1) * BUFE];
        const unsigned short* Bb = Ab + 16384;
#pragma unroll
        for (int c = 0; c < 4; ++c) stageA(t + 1, c);
#pragma unroll
        for (int c = 0; c < NF; ++c) stageB(t + 1, c);
        __builtin_amdgcn_sched_barrier(0);
        if constexpr (NF == 3) asm volatile("s_waitcnt vmcnt(7)" ::: "memory");
        else                   asm volatile("s_waitcnt vmcnt(6)" ::: "memory");
        __builtin_amdgcn_s_barrier();
        __builtin_amdgcn_sched_barrier(0);                 // no ds_read above validity
        compute(Ab, Bb);
        __builtin_amdgcn_s_barrier();   // all reads of buf done before t+2 staging
    }
    {
        const unsigned short* Ab = &lds[((NT - 1) & 1) * BUFE];
        const unsigned short* Bb = Ab + 16384;
        asm volatile("s_waitcnt vmcnt(0)" ::: "memory");
        __builtin_amdgcn_s_barrier();
        __builtin_amdgcn_sched_barrier(0);
        compute(Ab, Bb);
    }

    // epilogue: C/D map col=l16, row=l4*4+r (m89)
#pragma unroll
    for (int nf = 0; nf < NF; ++nf) {
        const long n = bn + wn * (NF * 16) + nf * 16 + l16;
        float bvv = 0.f;
        if (hasBias)
            bvv = (n < HID) ? bq[n] : ((n < 2 * HID) ? bk[n - HID] : bv[n - 2 * HID]);
#pragma unroll
        for (int mf = 0; mf < 8; ++mf) {
#pragma unroll
            for (int r = 0; r < 4; ++r) {
                const long m = bm + wm * 128 + mf * 16 + l4 * 4 + r;
                float v = acc[mf][nf][r] + bvv;
                if (F32OUT) Cf[m * (long)ldc + n] = v;
                else        Cb[m * (long)ldc + n] = f2bf(v);
            }
        }
    }
}

// ---------------- RoPE in place on Q,K halves; folds 1/sqrt(128) into Q ------
__global__ __launch_bounds__(256) void rope_kernel(unsigned short* __restrict__ qkv)
{
    int t = blockIdx.x * 256 + threadIdx.x;   // 1,048,576 total
    int j8 = t & 7;
    int h  = (t >> 3) & 15;
    int qk = (t >> 7) & 1;                    // 0 = Q, 1 = K
    int row = t >> 8;                         // 0..4095
    int s = row & (SEQ - 1);
    unsigned short* p = &qkv[(long)row * QKN + qk * HID + h * HD + j8 * 8];
    s16x8 lo = *(const s16x8*)p;
    s16x8 hi = *(const s16x8*)(p + 64);
    float qscale = qk ? 1.0f : 0.08838834764831845f;
    s16x8 olo, ohi;
#pragma unroll
    for (int e = 0; e < 8; ++e) {
        int j = j8 * 8 + e;                   // 0..63
        float inv = exp2f(-(float)j * 0.20762050593046f);  // 10000^(-j/64)
        float sn, cs;
        sincosf((float)s * inv, &sn, &cs);
        float x1 = bf2f((unsigned short)lo[e]);
        float x2 = bf2f((unsigned short)hi[e]);
        olo[e] = (short)f2bf((x1 * cs - x2 * sn) * qscale);
        ohi[e] = (short)f2bf((x2 * cs + x1 * sn) * qscale);
    }
    *(s16x8*)p = olo;
    *(s16x8*)(p + 64) = ohi;
}

// ---------------- V[b,s,h,d] -> VT[b,h,d,s] ----------------
__global__ __launch_bounds__(256) void v_transpose(
    const unsigned short* __restrict__ qkv, unsigned short* __restrict__ vt)
{
    __shared__ unsigned short t[32][33];
    int bh = blockIdx.z;
    int b = bh >> 4, h = bh & 15;
    int s0 = blockIdx.x * 32, d0 = blockIdx.y * 32;
    int tx = threadIdx.x & 31, ty = threadIdx.x >> 5;
#pragma unroll
    for (int r = ty; r < 32; r += 8)
        t[r][tx] = qkv[(long)(b * SEQ + s0 + r) * QKN + 2 * HID + h * HD + d0 + tx];
    __syncthreads();
#pragma unroll
    for (int r = ty; r < 32; r += 8)
        vt[((long)bh * HD + d0 + r) * SEQ + s0 + tx] = t[tx][r];
}

// -------- MFMA flash attention (r14 best-known): 8 waves / QBLK=128, T2
// swizzles, dbuf staging, defer-max, swapped-QK^T in-register softmax.
// XCD-chunked: each XCD owns 4 heads x 16 q-tiles (K/V L2-resident).
__global__ __launch_bounds__(512) void attn_kernel(
    const unsigned short* __restrict__ qkv,
    const unsigned short* __restrict__ vt,
    unsigned short* __restrict__ attnout)
{
    __shared__ unsigned short Ks[2][64 * 128];   // [kv][d], byte ^= (kv&7)<<4
    __shared__ unsigned short Vs[2][128 * 64];   // [d][kv], byte ^= (d&7)<<4

    const int tid = threadIdx.x, wid = tid >> 6, lane = tid & 63;
    const int l16 = lane & 15, l4 = lane >> 4;
    const int bid = blockIdx.x;                  // 0..511
    const int xcd = bid & 7, idx = bid >> 3;     // idx 0..63
    const int bh = xcd * 4 + (idx >> 4);         // 4 heads per XCD
    const int qt = idx & 15;                     // 16 q-tiles (QBLK=128)
    const int b = bh >> 4, h = bh & 15;
    const long rowbase = (long)b * SEQ;

    const unsigned short* Kg = &qkv[rowbase * QKN + HID + h * HD];  // + s*QKN
    const unsigned short* Vg = &vt[(long)bh * HD * SEQ];            // + d*SEQ

    // 16 K chunks + 16 V chunks over 8 waves -> 2+2 per wave
    auto stage = [&](int buf, int kv0) {
#pragma unroll
        for (int i = 0; i < 2; ++i) {
            int c = wid * 2 + i;
            int kr = c * 4 + l4;
            int kcb = (l16 * 16) ^ ((kr & 7) << 4);
            gload_lds16((const char*)(Kg + (long)(kv0 + kr) * QKN) + kcb, &Ks[buf][c * 512]);
            int vr = c * 8 + (lane >> 3);
            int vcb = ((lane & 7) * 16) ^ ((vr & 7) << 4);
            gload_lds16((const char*)(Vg + (long)vr * SEQ + kv0) + vcb, &Vs[buf][c * 512]);
        }
    };

    bf16x8 qf[4];
    {
        const long qrow = rowbase + qt * 128 + wid * 16 + l16;
        const unsigned short* qp = &qkv[qrow * QKN + h * HD];
#pragma unroll
        for (int kc = 0; kc < 4; ++kc) qf[kc] = ld_bf8(qp + kc * 32 + l4 * 8);
    }

    f32x4 o[8];
#pragma unroll
    for (int nb = 0; nb < 8; ++nb) o[nb] = f32x4{0.f, 0.f, 0.f, 0.f};
    float mrun = -3.0e38f, lrun = 0.f;       // per-lane scalars (q = l16)

    const int srcA = ((l4 & 1) * 2) * 16 + l16;   // lane of l4_s = 2(l4&1)
    const int srcB = srcA + 16;                   // lane of l4_s = 2(l4&1)+1
    const bool sel = (l4 >> 1) != 0;              // nf_s = 2kc + (l4>>1)

    stage(0, 0);
    __syncthreads();

    for (int t = 0; t < SEQ / 64; ++t) {
        const int cur = t & 1;
        if (t < SEQ / 64 - 1) stage(cur ^ 1, (t + 1) * 64);
        __builtin_amdgcn_sched_barrier(0);   // pin: issue next-tile stage first

        const unsigned short* Kc = &Ks[cur][0];
        const unsigned short* Vc = &Vs[cur][0];

        // S^T = K Q^T: A = kf (rows=kv), B = qf (cols=q)
        f32x4 sc[4];
#pragma unroll
        for (int nf = 0; nf < 4; ++nf) sc[nf] = f32x4{0.f, 0.f, 0.f, 0.f};
#pragma unroll
        for (int kc = 0; kc < 4; ++kc) {
#pragma unroll
            for (int nf = 0; nf < 4; ++nf) {
                int row = nf * 16 + l16;
                int cb = (kc * 64 + l4 * 16) ^ ((row & 7) << 4);
                bf16x8 kf = as_bf(*(const s16x8*)((const char*)Kc + row * 256 + cb));
                sc[nf] = __builtin_amdgcn_mfma_f32_16x16x32_bf16(kf, qf[kc], sc[nf], 0, 0, 0);
            }
        }

        // per-lane max over 16 values, then combine 4 l4-copies
        float tmax = sc[0][0];
#pragma unroll
        for (int nf = 0; nf < 4; ++nf)
#pragma unroll
            for (int r = 0; r < 4; ++r) tmax = fmaxf(tmax, sc[nf][r]);
        tmax = fmaxf(tmax, __shfl_xor(tmax, 16, 64));
        tmax = fmaxf(tmax, __shfl_xor(tmax, 32, 64));

        // defer-max (T13): skip rescale when max growth <= 8 (wave-uniform)
        if (!__all(tmax - mrun <= 8.0f)) {
            float mn = fmaxf(mrun, tmax);
            float sc_ = __expf(mrun - mn);
            mrun = mn;
            lrun *= sc_;
            float s_[4];
#pragma unroll
            for (int r = 0; r < 4; ++r) s_[r] = __shfl(sc_, l4 * 4 + r, 64);
#pragma unroll
            for (int nb = 0; nb < 8; ++nb)
#pragma unroll
                for (int r = 0; r < 4; ++r) o[nb][r] *= s_[r];
        }

        // P = exp(S - m); pack to bf16 pairs; sum
        unsigned pk[4][2];
        float sum = 0.f;
#pragma unroll
        for (int nf = 0; nf < 4; ++nf) {
            float p0 = __expf(sc[nf][0] - mrun);
            float p1 = __expf(sc[nf][1] - mrun);
            float p2 = __expf(sc[nf][2] - mrun);
            float p3 = __expf(sc[nf][3] - mrun);
            sum += (p0 + p1) + (p2 + p3);
            union { __bf16 b[2]; unsigned u; } w0, w1;
            w0.b[0] = (__bf16)p0; w0.b[1] = (__bf16)p1;
            w1.b[0] = (__bf16)p2; w1.b[1] = (__bf16)p3;
            pk[nf][0] = w0.u; pk[nf][1] = w1.u;
        }
        sum += __shfl_xor(sum, 16, 64);
        sum += __shfl_xor(sum, 32, 64);
        lrun += sum;

        // redistribute P into PV A-fragments (4-lane group exchange)
        union { unsigned u[4]; bf16x8 v; } pa0, pa1;
#pragma unroll
        for (int w = 0; w < 2; ++w) {
            unsigned a0 = __shfl(pk[0][w], srcA, 64);
            unsigned a1 = __shfl(pk[1][w], srcA, 64);
            unsigned b0 = __shfl(pk[0][w], srcB, 64);
            unsigned b1 = __shfl(pk[1][w], srcB, 64);
            pa0.u[w]     = sel ? a1 : a0;
            pa0.u[2 + w] = sel ? b1 : b0;
            unsigned c0 = __shfl(pk[2][w], srcA, 64);
            unsigned c1 = __shfl(pk[3][w], srcA, 64);
            unsigned d0 = __shfl(pk[2][w], srcB, 64);
            unsigned d1 = __shfl(pk[3][w], srcB, 64);
            pa1.u[w]     = sel ? c1 : c0;
            pa1.u[2 + w] = sel ? d1 : d0;
        }

        // O += P V   (A = pa (q rows), B = V^T [d][kv] swizzled)
#pragma unroll
        for (int kc = 0; kc < 2; ++kc) {
            bf16x8 pav = kc ? pa1.v : pa0.v;
#pragma unroll
            for (int nb = 0; nb < 8; ++nb) {
                int vrow = nb * 16 + l16;
                int vcb = (kc * 64 + l4 * 16) ^ ((vrow & 7) << 4);
                bf16x8 vb = as_bf(*(const s16x8*)((const char*)Vc + vrow * 128 + vcb));
                o[nb] = __builtin_amdgcn_mfma_f32_16x16x32_bf16(pav, vb, o[nb], 0, 0, 0);
            }
        }
        __syncthreads();   // implicit vmcnt(0): next-tile stage (issued pre-compute) done
    }

    // stats live at q=l16 lanes; o rows are q=l4*4+r -> hop via 4 shuffles
    float linv = 1.f / lrun;
    float li[4];
#pragma unroll
    for (int r = 0; r < 4; ++r) li[r] = __shfl(linv, l4 * 4 + r, 64);
#pragma unroll
    for (int r = 0; r < 4; ++r) {
        long m = rowbase + qt * 128 + wid * 16 + l4 * 4 + r;
#pragma unroll
        for (int nb = 0; nb < 8; ++nb)
            attnout[m * HID + h * HD + nb * 16 + l16] = f2bf(o[nb][r] * li[r]);
    }
}

// ---------------- launch ----------------
extern "C" void kernel_launch(void* const* d_in, const int* in_sizes, int n_in,
                              void* d_out, int out_size, void* d_ws, size_t ws_size,
                              hipStream_t stream)
{
    const float* hs = (const float*)d_in[0];
    const float* Wq = (const float*)d_in[1];
    const float* bq = (const float*)d_in[2];
    const float* Wk = (const float*)d_in[3];
    const float* bk = (const float*)d_in[4];
    const float* Wv = (const float*)d_in[5];
    const float* bv = (const float*)d_in[6];
    const float* Wo = (const float*)d_in[7];
    float* out = (float*)d_out;   // fp32 output (confirmed round 5)

    bool shapes_ok =
        (n_in == 8) && (out_size == 8388608) &&
        in_sizes[0] == 8388608 && in_sizes[1] == 4194304 && in_sizes[2] == 2048 &&
        in_sizes[3] == 4194304 && in_sizes[4] == 2048 && in_sizes[5] == 4194304 &&
        in_sizes[6] == 2048 && in_sizes[7] == 4194304;
    if (!shapes_ok || ws_size < 117440512ull) {
        fill_f32<<<32768, 256, 0, stream>>>(out, shapes_ok ? 1000.f : 0.f, out_size);
        return;
    }

    char* ws = (char*)d_ws;
    unsigned short* hsB     = (unsigned short*)(ws);              // [4096][2048] bf16
    unsigned short* qkvB    = (unsigned short*)(ws + 16777216);   // [4096][6144] bf16
    unsigned short* wqkvT   = (unsigned short*)(ws + 67108864);   // [6144][2048] bf16
    unsigned short* vtB     = (unsigned short*)(ws + 92274688);   // [32][128][2048] bf16
    unsigned short* woT     = (unsigned short*)(ws + 109051904);  // [2048][2048] bf16
    unsigned short* attnout = hsB;   // hsB dead after QKV GEMM

    convert_f32_bf16<<<4096, 256, 0, stream>>>(hs, hsB);
    dim3 tg(64, 64);
    transpose_w<<<tg, 256, 0, stream>>>(Wq, wqkvT);
    transpose_w<<<tg, 256, 0, stream>>>(Wk, wqkvT + 2048 * 2048);
    transpose_w<<<tg, 256, 0, stream>>>(Wv, wqkvT + 2 * 2048 * 2048);
    transpose_w<<<tg, 256, 0, stream>>>(Wo, woT);

    // QKV: 256x192 tiles, 16x32 grid, XCD chunks 8x8
    gemm_8phase<3, false><<<dim3(512), 512, 0, stream>>>(
        hsB, wqkvT, bq, bk, bv, qkvB, nullptr, 2048, QKN, 32, 8, 8, 1);
    rope_kernel<<<4096, 256, 0, stream>>>(qkvB);
    v_transpose<<<dim3(64, 4, 32), 256, 0, stream>>>(qkvB, vtB);
    // attn: QBLK=128, 8 waves, 512 blocks, XCD-chunked (4 heads x 16 qt per XCD)
    attn_kernel<<<dim3(512), 512, 0, stream>>>(qkvB, vtB, attnout);
    // out-proj: 256x128 tiles, 16x16 grid, XCD chunks 4x8, fp32 out
    gemm_8phase<2, true><<<dim3(256), 512, 0, stream>>>(
        attnout, woT, nullptr, nullptr, nullptr, nullptr, out, 2048, HID, 16, 4, 8, 0);
}